// Round 4
// baseline (228.382 us; speedup 1.0000x reference)
//
#include <hip/hip_runtime.h>

// Problem: B=32, N=384, C=768, H=12, hd=64, scale=1/8, EPS=1e-6
#define BB 32
#define NN 384
#define CC 768
#define HH 12
#define HD 64

typedef __attribute__((ext_vector_type(4))) float f32x4;
typedef __attribute__((ext_vector_type(8))) __bf16 bf16x8;
typedef __attribute__((ext_vector_type(4))) __bf16 bf16x4;

static __device__ __forceinline__ f32x4 mfma16(bf16x8 a, bf16x8 b, f32x4 c) {
    return __builtin_amdgcn_mfma_f32_16x16x32_bf16(a, b, c, 0, 0, 0);
}

// async global->LDS DMA, 16B per lane. LDS dest is WAVE-UNIFORM base; HW adds lane*16.
static __device__ __forceinline__ void gload_lds16(const void* g, void* l) {
    __builtin_amdgcn_global_load_lds((const __attribute__((address_space(1))) void*)g,
                                     (__attribute__((address_space(3))) void*)l, 16, 0, 0);
}

// ---------------- fused f32 -> bf16 convert (all 3 sources, 1 launch) ------
// dst = ws[0 .. 11796480) contiguous: xb | wqkv(Q-part scaled) | wproj
#define XU   1179648   // x units (of 8 elem)
#define QU   73728     // qkv_w Q-part units
#define QKVU 221184    // qkv_w total units
#define PU   73728     // proj_w units
__global__ void cvt_kernel(const float* __restrict__ x, const float* __restrict__ qkv_w,
                           const float* __restrict__ proj_w, __bf16* __restrict__ dst) {
    const int i = blockIdx.x * blockDim.x + threadIdx.x;
    if (i >= XU + QKVU + PU) return;
    const float* src;
    float sc = 1.f;
    if (i < XU) src = x + (size_t)i * 8;
    else if (i < XU + QKVU) {
        src = qkv_w + (size_t)(i - XU) * 8;
        if (i < XU + QU) sc = 0.125f;  // Q weight rows pre-scaled by softmax scale
    } else src = proj_w + (size_t)(i - XU - QKVU) * 8;
    f32x4 a = *(const f32x4*)src;
    f32x4 b = *(const f32x4*)(src + 4);
    bf16x8 o;
#pragma unroll
    for (int j = 0; j < 4; ++j) { o[j] = (__bf16)(a[j] * sc); o[j + 4] = (__bf16)(b[j] * sc); }
    *(bf16x8*)(dst + (size_t)i * 8) = o;
}

// ---------------- GEMM: C[M][ncol] = A[M][768] * Bw[ncol][768]^T + bias ----
// m97 structure: 128x128 tile, BK=64, single LDS buffer, global_load_lds staging.
template <int EPI>
__global__ __launch_bounds__(256, 4) void gemm_kernel(
    const __bf16* __restrict__ A, const __bf16* __restrict__ Bw,
    const float* __restrict__ bias,
    __bf16* __restrict__ qkbuf, __bf16* __restrict__ vtbuf,
    float* __restrict__ fout) {
    __shared__ __bf16 Alds[128 * 64];
    __shared__ __bf16 Blds[128 * 64];

    const int tid = threadIdx.x;
    const int l = tid & 63;
    const int w = tid >> 6;
    const int g = l >> 4, q16 = l & 15;
    const int mb = blockIdx.x * 128;
    const int nb = blockIdx.y * 128;
    const int wrb = (w >> 1) * 64;
    const int wcb = (w & 1) * 64;
    const int srow = w * 8 + (l >> 3);
    const int scol = (l & 7) * 8;

    f32x4 acc[4][4] = {};

    for (int kt = 0; kt < 12; ++kt) {
        const int kof = kt * 64 + scol;
#pragma unroll
        for (int i = 0; i < 4; ++i) {
            gload_lds16(&A[(size_t)(mb + i * 32 + srow) * CC + kof], &Alds[i * 2048 + w * 512]);
            gload_lds16(&Bw[(size_t)(nb + i * 32 + srow) * CC + kof], &Blds[i * 2048 + w * 512]);
        }
        __syncthreads();
#pragma unroll
        for (int c = 0; c < 2; ++c) {
            bf16x8 af[4], bfr[4];
#pragma unroll
            for (int m = 0; m < 4; ++m)
                af[m] = *(const bf16x8*)&Alds[(wrb + m * 16 + q16) * 64 + c * 32 + g * 8];
#pragma unroll
            for (int n = 0; n < 4; ++n)
                bfr[n] = *(const bf16x8*)&Blds[(wcb + n * 16 + q16) * 64 + c * 32 + g * 8];
#pragma unroll
            for (int m = 0; m < 4; ++m)
#pragma unroll
                for (int n = 0; n < 4; ++n)
                    acc[m][n] = mfma16(af[m], bfr[n], acc[m][n]);
        }
        __syncthreads();
    }

    // epilogue. C/D layout: col = q16 (+16*n), row = 4*g + r (+16*m)
    if constexpr (EPI == 0) {
        const int bbatch = mb / NN;
        const int tokb = mb % NN;
#pragma unroll
        for (int n = 0; n < 4; ++n) {
            const int colb = nb + wcb + n * 16;
            const int col = colb + q16;
            float bs = bias[col];
            if (colb < 2 * CC) {
                if (colb < CC) bs *= 0.125f;
#pragma unroll
                for (int m = 0; m < 4; ++m) {
                    const int row = mb + wrb + m * 16 + g * 4;
#pragma unroll
                    for (int r = 0; r < 4; ++r)
                        qkbuf[(size_t)(row + r) * 1536 + col] = (__bf16)(acc[m][n][r] + bs);
                }
            } else {
                const int dd = (col - 2 * CC) & 63;
                const int hh = (colb - 2 * CC) >> 6;
                __bf16* vp = vtbuf + ((size_t)(bbatch * HH + hh) * HD + dd) * NN;
#pragma unroll
                for (int m = 0; m < 4; ++m) {
                    const int tok = tokb + wrb + m * 16 + g * 4;
                    bf16x4 pk;
#pragma unroll
                    for (int r = 0; r < 4; ++r) pk[r] = (__bf16)(acc[m][n][r] + bs);
                    *(bf16x4*)&vp[tok] = pk;
                }
            }
        }
    } else {
#pragma unroll
        for (int n = 0; n < 4; ++n) {
            const int col = nb + wcb + n * 16 + q16;
            const float bs = bias[col];
#pragma unroll
            for (int m = 0; m < 4; ++m)
#pragma unroll
                for (int r = 0; r < 4; ++r)
                    fout[(size_t)(mb + wrb + m * 16 + g * 4 + r) * CC + col] = acc[m][n][r] + bs;
        }
    }
}

// ---------------- fused policy-softmax attention ----------------
// ONE block per (b,h): grid 384, 512 threads (8 waves x 16 queries x 3 passes).
// K (48KB) and V^T (48KB) staged ONCE via global_load_lds, both XOR-swizzled
// (linear LDS dest + inverse-swizzled per-lane global source + swizzled read).
// Single barrier; passes are barrier-free (LDS read-only).
// __launch_bounds__(512,1): LDS (97.5KB) caps at 1 block/CU regardless; the
// previous (512,2) capped VGPR at 128 and spilled ~163MB/dispatch to scratch.
__global__ __launch_bounds__(512, 1) void attn_kernel(
    const __bf16* __restrict__ qkbuf, const __bf16* __restrict__ vtbuf,
    const float* __restrict__ policy, __bf16* __restrict__ attb) {
    __shared__ __bf16 Klds[NN * HD];  // [row][128B], swz: byte ^= (row&7)<<4
    __shared__ __bf16 Vlds[HD * NN];  // [row][768B], swz: byte ^= (row&7)<<4
    __shared__ float pol[NN];

    const int tid = threadIdx.x;
    const int l = tid & 63;
    const int w = tid >> 6;
    const int g = l >> 4, q16 = l & 15;
    const int bh = blockIdx.x;
    const int b = bh / HH, h = bh % HH;

    // K stage: chunk cs -> row cs>>3 (128B rows), in-row chunk (cs&7)^(row&7) of global
    const __bf16* kg = qkbuf + (size_t)b * NN * 1536 + CC + h * HD;
#pragma unroll
    for (int p = 0; p < 6; ++p) {
        const int cs = p * 512 + w * 64 + l;
        const int row = cs >> 3, cin = cs & 7;
        gload_lds16(&kg[(size_t)row * 1536 + (size_t)((cin ^ (row & 7)) << 3)],
                    &Klds[(p * 512 + w * 64) * 8]);
    }
    // V stage: row stride 48 chunks; XOR only low 3 chunk bits (48 = 6*8, bijective)
    const __bf16* vg = vtbuf + (size_t)(b * HH + h) * HD * NN;
#pragma unroll
    for (int p = 0; p < 6; ++p) {
        const int cs = p * 512 + w * 64 + l;
        const int row = cs / 48, cin = cs - row * 48;
        gload_lds16(&vg[row * NN + ((cin ^ (row & 7)) << 3)], &Vlds[(p * 512 + w * 64) * 8]);
    }
    for (int i = tid; i < NN; i += 512) pol[i] = policy[b * NN + i];

    // prefetch Q fragments for all 3 passes (B-operand: lane holds its query's row)
    bf16x8 qf[3][2];
#pragma unroll
    for (int ps = 0; ps < 3; ++ps) {
        const int qrow = ps * 128 + w * 16 + q16;
        const __bf16* qg = qkbuf + ((size_t)b * NN + qrow) * 1536 + h * HD;
        qf[ps][0] = *(const bf16x8*)&qg[g * 8];
        qf[ps][1] = *(const bf16x8*)&qg[32 + g * 8];
    }
    __syncthreads();  // drains DMA (vmcnt) + pol writes

    const int sw = (q16 & 7) << 4;  // swizzle term: row&7 == q16&7 for all our rows

#pragma unroll
    for (int ps = 0; ps < 3; ++ps) {
        const int qrow = ps * 128 + w * 16 + q16;

        // S^T = K*Q^T: st[t][r] = S[key=16t+4g+r][q=q16]
        f32x4 st[24];
        __builtin_amdgcn_s_setprio(1);
#pragma unroll
        for (int t = 0; t < 24; ++t) {
            const int byte0 = (t * 16 + q16) * 128 + g * 16;
            bf16x8 k0 = *(const bf16x8*)((const char*)Klds + (byte0 ^ sw));
            bf16x8 k1 = *(const bf16x8*)((const char*)Klds + ((byte0 + 64) ^ sw));
            f32x4 z = {0.f, 0.f, 0.f, 0.f};
            st[t] = mfma16(k1, qf[ps][1], mfma16(k0, qf[ps][0], z));
        }
        __builtin_amdgcn_s_setprio(0);

        // max over ALL keys (reference maxes before masking)
        float mx = -1e30f;
#pragma unroll
        for (int t = 0; t < 24; ++t)
#pragma unroll
            for (int r = 0; r < 4; ++r) mx = fmaxf(mx, st[t][r]);
        mx = fmaxf(mx, __shfl_xor(mx, 16));
        mx = fmaxf(mx, __shfl_xor(mx, 32));

        float sum = 0.f;
#pragma unroll
        for (int t = 0; t < 24; ++t) {
#pragma unroll
            for (int r = 0; r < 4; ++r) {
                const int key = t * 16 + g * 4 + r;
                const bool keep = (pol[key] > 0.5f) || (key == qrow);
                const float e = keep ? __expf(st[t][r] - mx) : 0.f;
                st[t][r] = e;
                sum += e;
            }
        }
        sum += __shfl_xor(sum, 16);
        sum += __shfl_xor(sum, 32);
        const float dinv = 1.f / (sum + 1e-6f);  // EPS/n numerator ~1e-9: dropped

        // PV: P k-slots lane-local (A/B share k-slot bijection)
        f32x4 oacc[4] = {};
        __builtin_amdgcn_s_setprio(1);
#pragma unroll
        for (int c = 0; c < 12; ++c) {
            bf16x8 pf;
#pragma unroll
            for (int r = 0; r < 4; ++r) {
                pf[r] = (__bf16)st[2 * c][r];
                pf[r + 4] = (__bf16)st[2 * c + 1][r];
            }
#pragma unroll
            for (int db = 0; db < 4; ++db) {
                const int byte0 = (db * 16 + q16) * 768 + c * 64 + g * 8;
                bf16x4 v0 = *(const bf16x4*)((const char*)Vlds + (byte0 ^ sw));
                bf16x4 v1 = *(const bf16x4*)((const char*)Vlds + ((byte0 + 32) ^ sw));
                bf16x8 vf;
#pragma unroll
                for (int r = 0; r < 4; ++r) { vf[r] = v0[r]; vf[r + 4] = v1[r]; }
                oacc[db] = mfma16(vf, pf, oacc[db]);
            }
        }
        __builtin_amdgcn_s_setprio(0);

        __bf16* op = attb + ((size_t)b * NN + qrow) * CC + h * HD;
#pragma unroll
        for (int db = 0; db < 4; ++db) {
            bf16x4 pk;
#pragma unroll
            for (int r = 0; r < 4; ++r) pk[r] = (__bf16)(oacc[db][r] * dinv);
            *(bf16x4*)&op[db * 16 + g * 4] = pk;
        }
    }
}

extern "C" void kernel_launch(void* const* d_in, const int* in_sizes, int n_in,
                              void* d_out, int out_size, void* d_ws, size_t ws_size,
                              hipStream_t stream) {
    (void)in_sizes; (void)n_in; (void)out_size; (void)ws_size;
    const float* x      = (const float*)d_in[0];
    const float* policy = (const float*)d_in[1];
    const float* qkv_w  = (const float*)d_in[2];
    const float* qkv_b  = (const float*)d_in[3];
    const float* proj_w = (const float*)d_in[4];
    const float* proj_b = (const float*)d_in[5];
    float* out = (float*)d_out;

    // workspace layout (bf16), total ~94.5 MB
    __bf16* xb    = (__bf16*)d_ws;                     // 12288*768
    __bf16* wqkv  = xb + (size_t)12288 * 768;          // 2304*768
    __bf16* wproj = wqkv + (size_t)2304 * 768;         // 768*768
    __bf16* qkbuf = wproj + (size_t)768 * 768;         // 12288*1536 (Q|K)
    __bf16* vtbuf = qkbuf + (size_t)12288 * 1536;      // 32*12*64*384 (V^T)
    __bf16* attb  = vtbuf + (size_t)BB * HH * HD * NN; // 12288*768

    const int units = XU + QKVU + PU;
    cvt_kernel<<<(units + 255) / 256, 256, 0, stream>>>(x, qkv_w, proj_w, xb);

    gemm_kernel<0><<<dim3(96, 18), 256, 0, stream>>>(xb, wqkv, qkv_b, qkbuf, vtbuf, nullptr);
    attn_kernel<<<384, 512, 0, stream>>>(qkbuf, vtbuf, policy, attb);
    gemm_kernel<1><<<dim3(96, 6), 256, 0, stream>>>(attb, wproj, proj_b, nullptr, nullptr, out);
}

// Round 5
// 198.922 us; speedup vs baseline: 1.1481x; 1.1481x over previous
//
#include <hip/hip_runtime.h>

// Problem: B=32, N=384, C=768, H=12, hd=64, scale=1/8, EPS=1e-6
#define BB 32
#define NN 384
#define CC 768
#define HH 12
#define HD 64

typedef __attribute__((ext_vector_type(4))) float f32x4;
typedef __attribute__((ext_vector_type(8))) __bf16 bf16x8;
typedef __attribute__((ext_vector_type(4))) __bf16 bf16x4;

static __device__ __forceinline__ f32x4 mfma16(bf16x8 a, bf16x8 b, f32x4 c) {
    return __builtin_amdgcn_mfma_f32_16x16x32_bf16(a, b, c, 0, 0, 0);
}

// async global->LDS DMA, 16B per lane. LDS dest is WAVE-UNIFORM base; HW adds lane*16.
static __device__ __forceinline__ void gload_lds16(const void* g, void* l) {
    __builtin_amdgcn_global_load_lds((const __attribute__((address_space(1))) void*)g,
                                     (__attribute__((address_space(3))) void*)l, 16, 0, 0);
}

// ---------------- fused f32 -> bf16 convert (all 3 sources, 1 launch) ------
#define XU   1179648   // x units (of 8 elem)
#define QU   73728     // qkv_w Q-part units
#define QKVU 221184    // qkv_w total units
#define PU   73728     // proj_w units
__global__ void cvt_kernel(const float* __restrict__ x, const float* __restrict__ qkv_w,
                           const float* __restrict__ proj_w, __bf16* __restrict__ dst) {
    const int i = blockIdx.x * blockDim.x + threadIdx.x;
    if (i >= XU + QKVU + PU) return;
    const float* src;
    float sc = 1.f;
    if (i < XU) src = x + (size_t)i * 8;
    else if (i < XU + QKVU) {
        src = qkv_w + (size_t)(i - XU) * 8;
        if (i < XU + QU) sc = 0.125f;  // Q weight rows pre-scaled by softmax scale
    } else src = proj_w + (size_t)(i - XU - QKVU) * 8;
    f32x4 a = *(const f32x4*)src;
    f32x4 b = *(const f32x4*)(src + 4);
    bf16x8 o;
#pragma unroll
    for (int j = 0; j < 4; ++j) { o[j] = (__bf16)(a[j] * sc); o[j + 4] = (__bf16)(b[j] * sc); }
    *(bf16x8*)(dst + (size_t)i * 8) = o;
}

// ---------------- GEMM: C[M][ncol] = A[M][768] * Bw[ncol][768]^T + bias ----
template <int EPI>
__global__ __launch_bounds__(256, 4) void gemm_kernel(
    const __bf16* __restrict__ A, const __bf16* __restrict__ Bw,
    const float* __restrict__ bias,
    __bf16* __restrict__ qkbuf, __bf16* __restrict__ vtbuf,
    float* __restrict__ fout) {
    __shared__ __bf16 Alds[128 * 64];
    __shared__ __bf16 Blds[128 * 64];

    const int tid = threadIdx.x;
    const int l = tid & 63;
    const int w = tid >> 6;
    const int g = l >> 4, q16 = l & 15;
    const int mb = blockIdx.x * 128;
    const int nb = blockIdx.y * 128;
    const int wrb = (w >> 1) * 64;
    const int wcb = (w & 1) * 64;
    const int srow = w * 8 + (l >> 3);
    const int scol = (l & 7) * 8;

    f32x4 acc[4][4] = {};

    for (int kt = 0; kt < 12; ++kt) {
        const int kof = kt * 64 + scol;
#pragma unroll
        for (int i = 0; i < 4; ++i) {
            gload_lds16(&A[(size_t)(mb + i * 32 + srow) * CC + kof], &Alds[i * 2048 + w * 512]);
            gload_lds16(&Bw[(size_t)(nb + i * 32 + srow) * CC + kof], &Blds[i * 2048 + w * 512]);
        }
        __syncthreads();
#pragma unroll
        for (int c = 0; c < 2; ++c) {
            bf16x8 af[4], bfr[4];
#pragma unroll
            for (int m = 0; m < 4; ++m)
                af[m] = *(const bf16x8*)&Alds[(wrb + m * 16 + q16) * 64 + c * 32 + g * 8];
#pragma unroll
            for (int n = 0; n < 4; ++n)
                bfr[n] = *(const bf16x8*)&Blds[(wcb + n * 16 + q16) * 64 + c * 32 + g * 8];
#pragma unroll
            for (int m = 0; m < 4; ++m)
#pragma unroll
                for (int n = 0; n < 4; ++n)
                    acc[m][n] = mfma16(af[m], bfr[n], acc[m][n]);
        }
        __syncthreads();
    }

    // epilogue. C/D layout: col = q16 (+16*n), row = 4*g + r (+16*m)
    if constexpr (EPI == 0) {
        const int bbatch = mb / NN;
        const int tokb = mb % NN;
#pragma unroll
        for (int n = 0; n < 4; ++n) {
            const int colb = nb + wcb + n * 16;
            const int col = colb + q16;
            float bs = bias[col];
            if (colb < 2 * CC) {
                if (colb < CC) bs *= 0.125f;
#pragma unroll
                for (int m = 0; m < 4; ++m) {
                    const int row = mb + wrb + m * 16 + g * 4;
#pragma unroll
                    for (int r = 0; r < 4; ++r)
                        qkbuf[(size_t)(row + r) * 1536 + col] = (__bf16)(acc[m][n][r] + bs);
                }
            } else {
                const int dd = (col - 2 * CC) & 63;
                const int hh = (colb - 2 * CC) >> 6;
                __bf16* vp = vtbuf + ((size_t)(bbatch * HH + hh) * HD + dd) * NN;
#pragma unroll
                for (int m = 0; m < 4; ++m) {
                    const int tok = tokb + wrb + m * 16 + g * 4;
                    bf16x4 pk;
#pragma unroll
                    for (int r = 0; r < 4; ++r) pk[r] = (__bf16)(acc[m][n][r] + bs);
                    *(bf16x4*)&vp[tok] = pk;
                }
            }
        }
    } else {
#pragma unroll
        for (int n = 0; n < 4; ++n) {
            const int col = nb + wcb + n * 16 + q16;
            const float bs = bias[col];
#pragma unroll
            for (int m = 0; m < 4; ++m)
#pragma unroll
                for (int r = 0; r < 4; ++r)
                    fout[(size_t)(mb + wrb + m * 16 + g * 4 + r) * CC + col] = acc[m][n][r] + bs;
        }
    }
}

// ---------------- fused policy-softmax attention (online softmax) ----------
// ONE block per (b,h): grid 384, 512 threads (8 waves x 16 queries x 3 passes).
// K/V staged ONCE into swizzled LDS; passes barrier-free. ONLINE softmax over
// 3 key-tiles of 128 keeps per-thread state at st[8] (32 VGPR) instead of
// st[24] (96) -- rounds 3/4 spilled ~163MB/dispatch at the 128-VGPR target.
// Running max is over ALL keys (mask only gates e), matching the reference.
__global__ __launch_bounds__(512, 1) void attn_kernel(
    const __bf16* __restrict__ qkbuf, const __bf16* __restrict__ vtbuf,
    const float* __restrict__ policy, __bf16* __restrict__ attb) {
    __shared__ __bf16 Klds[NN * HD];  // [row][128B], swz: byte ^= (row&7)<<4
    __shared__ __bf16 Vlds[HD * NN];  // [row][768B], swz: byte ^= (row&7)<<4
    __shared__ float pol[NN];

    const int tid = threadIdx.x;
    const int l = tid & 63;
    const int w = tid >> 6;
    const int g = l >> 4, q16 = l & 15;
    const int bh = blockIdx.x;
    const int b = bh / HH, h = bh % HH;

    // K stage: chunk cs -> row cs>>3 (128B rows), in-row chunk (cs&7)^(row&7)
    const __bf16* kg = qkbuf + (size_t)b * NN * 1536 + CC + h * HD;
#pragma unroll
    for (int p = 0; p < 6; ++p) {
        const int cs = p * 512 + w * 64 + l;
        const int row = cs >> 3, cin = cs & 7;
        gload_lds16(&kg[(size_t)row * 1536 + (size_t)((cin ^ (row & 7)) << 3)],
                    &Klds[(p * 512 + w * 64) * 8]);
    }
    // V stage: rows of 48 chunks; XOR low 3 chunk bits (bijective within row)
    const __bf16* vg = vtbuf + (size_t)(b * HH + h) * HD * NN;
#pragma unroll
    for (int p = 0; p < 6; ++p) {
        const int cs = p * 512 + w * 64 + l;
        const int row = cs / 48, cin = cs - row * 48;
        gload_lds16(&vg[row * NN + ((cin ^ (row & 7)) << 3)], &Vlds[(p * 512 + w * 64) * 8]);
    }
    for (int i = tid; i < NN; i += 512) pol[i] = policy[b * NN + i];

    // prefetch Q fragments for all 3 passes
    bf16x8 qf[3][2];
#pragma unroll
    for (int ps = 0; ps < 3; ++ps) {
        const int qrow = ps * 128 + w * 16 + q16;
        const __bf16* qg = qkbuf + ((size_t)b * NN + qrow) * 1536 + h * HD;
        qf[ps][0] = *(const bf16x8*)&qg[g * 8];
        qf[ps][1] = *(const bf16x8*)&qg[32 + g * 8];
    }
    __syncthreads();  // drains DMA (vmcnt) + pol writes

    const int sw = (q16 & 7) << 4;  // row&7 == q16&7 for all rows we touch

#pragma unroll
    for (int ps = 0; ps < 3; ++ps) {
        const int qrow = ps * 128 + w * 16 + q16;
        float m = -1e30f, sum = 0.f;
        f32x4 oacc[4] = {};

#pragma unroll
        for (int kt = 0; kt < 3; ++kt) {
            // S^T tile: st[t][r] = S[key = kt*128 + 16t + 4g + r][q = q16]
            f32x4 st[8];
            __builtin_amdgcn_s_setprio(1);
#pragma unroll
            for (int t = 0; t < 8; ++t) {
                const int byte0 = ((kt * 8 + t) * 16 + q16) * 128 + g * 16;
                bf16x8 k0 = *(const bf16x8*)((const char*)Klds + (byte0 ^ sw));
                bf16x8 k1 = *(const bf16x8*)((const char*)Klds + ((byte0 + 64) ^ sw));
                f32x4 z = {0.f, 0.f, 0.f, 0.f};
                st[t] = mfma16(k1, qf[ps][1], mfma16(k0, qf[ps][0], z));
            }
            __builtin_amdgcn_s_setprio(0);

            // tile max over ALL keys (unmasked, as in reference)
            float tmx = -1e30f;
#pragma unroll
            for (int t = 0; t < 8; ++t)
#pragma unroll
                for (int r = 0; r < 4; ++r) tmx = fmaxf(tmx, st[t][r]);
            tmx = fmaxf(tmx, __shfl_xor(tmx, 16));
            tmx = fmaxf(tmx, __shfl_xor(tmx, 32));

            // unconditional online rescale (uniform within each query group)
            const float newm = fmaxf(m, tmx);
            const float f = __expf(m - newm);  // m=-1e30 first tile -> f=0
            m = newm;
            sum *= f;
#pragma unroll
            for (int db = 0; db < 4; ++db) oacc[db] *= f;

            // e = keep ? exp(s-m) : 0
#pragma unroll
            for (int t = 0; t < 8; ++t)
#pragma unroll
                for (int r = 0; r < 4; ++r) {
                    const int key = kt * 128 + t * 16 + g * 4 + r;
                    const bool keep = (pol[key] > 0.5f) || (key == qrow);
                    const float e = keep ? __expf(st[t][r] - m) : 0.f;
                    st[t][r] = e;
                    sum += e;
                }

            // PV accumulate for this tile (P k-slots lane-local)
            __builtin_amdgcn_s_setprio(1);
#pragma unroll
            for (int c4 = 0; c4 < 4; ++c4) {
                bf16x8 pf;
#pragma unroll
                for (int r = 0; r < 4; ++r) {
                    pf[r] = (__bf16)st[2 * c4][r];
                    pf[r + 4] = (__bf16)st[2 * c4 + 1][r];
                }
                const int c = kt * 4 + c4;
#pragma unroll
                for (int db = 0; db < 4; ++db) {
                    const int byte0 = (db * 16 + q16) * 768 + c * 64 + g * 8;
                    bf16x4 v0 = *(const bf16x4*)((const char*)Vlds + (byte0 ^ sw));
                    bf16x4 v1 = *(const bf16x4*)((const char*)Vlds + ((byte0 + 32) ^ sw));
                    bf16x8 vf;
#pragma unroll
                    for (int r = 0; r < 4; ++r) { vf[r] = v0[r]; vf[r + 4] = v1[r]; }
                    oacc[db] = mfma16(vf, pf, oacc[db]);
                }
            }
            __builtin_amdgcn_s_setprio(0);
        }

        sum += __shfl_xor(sum, 16);
        sum += __shfl_xor(sum, 32);
        const float dinv = 1.f / (sum + 1e-6f);  // EPS/n numerator ~1e-9: dropped

        __bf16* op = attb + ((size_t)b * NN + qrow) * CC + h * HD;
#pragma unroll
        for (int db = 0; db < 4; ++db) {
            bf16x4 pk;
#pragma unroll
            for (int r = 0; r < 4; ++r) pk[r] = (__bf16)(oacc[db][r] * dinv);
            *(bf16x4*)&op[db * 16 + g * 4] = pk;
        }
    }
}

extern "C" void kernel_launch(void* const* d_in, const int* in_sizes, int n_in,
                              void* d_out, int out_size, void* d_ws, size_t ws_size,
                              hipStream_t stream) {
    (void)in_sizes; (void)n_in; (void)out_size; (void)ws_size;
    const float* x      = (const float*)d_in[0];
    const float* policy = (const float*)d_in[1];
    const float* qkv_w  = (const float*)d_in[2];
    const float* qkv_b  = (const float*)d_in[3];
    const float* proj_w = (const float*)d_in[4];
    const float* proj_b = (const float*)d_in[5];
    float* out = (float*)d_out;

    // workspace layout (bf16), total ~94.5 MB
    __bf16* xb    = (__bf16*)d_ws;                     // 12288*768
    __bf16* wqkv  = xb + (size_t)12288 * 768;          // 2304*768
    __bf16* wproj = wqkv + (size_t)2304 * 768;         // 768*768
    __bf16* qkbuf = wproj + (size_t)768 * 768;         // 12288*1536 (Q|K)
    __bf16* vtbuf = qkbuf + (size_t)12288 * 1536;      // 32*12*64*384 (V^T)
    __bf16* attb  = vtbuf + (size_t)BB * HH * HD * NN; // 12288*768

    const int units = XU + QKVU + PU;
    cvt_kernel<<<(units + 255) / 256, 256, 0, stream>>>(x, qkv_w, proj_w, xb);

    gemm_kernel<0><<<dim3(96, 18), 256, 0, stream>>>(xb, wqkv, qkv_b, qkbuf, vtbuf, nullptr);
    attn_kernel<<<384, 512, 0, stream>>>(qkbuf, vtbuf, policy, attb);
    gemm_kernel<1><<<dim3(96, 6), 256, 0, stream>>>(attb, wproj, proj_b, nullptr, nullptr, out);
}

// Round 6
// 150.251 us; speedup vs baseline: 1.5200x; 1.3239x over previous
//
#include <hip/hip_runtime.h>

// Problem: B=32, N=384, C=768, H=12, hd=64, scale=1/8, EPS=1e-6
#define BB 32
#define NN 384
#define CC 768
#define HH 12
#define HD 64

typedef __attribute__((ext_vector_type(4))) float f32x4;
typedef __attribute__((ext_vector_type(8))) __bf16 bf16x8;
typedef __attribute__((ext_vector_type(4))) __bf16 bf16x4;

static __device__ __forceinline__ f32x4 mfma16(bf16x8 a, bf16x8 b, f32x4 c) {
    return __builtin_amdgcn_mfma_f32_16x16x32_bf16(a, b, c, 0, 0, 0);
}

// async global->LDS DMA, 16B per lane. LDS dest is WAVE-UNIFORM base; HW adds lane*16.
static __device__ __forceinline__ void gload_lds16(const void* g, void* l) {
    __builtin_amdgcn_global_load_lds((const __attribute__((address_space(1))) void*)g,
                                     (__attribute__((address_space(3))) void*)l, 16, 0, 0);
}

// ---------------- fused f32 -> bf16 convert (all 3 sources, 1 launch) ------
#define XU   1179648   // x units (of 8 elem)
#define QU   73728     // qkv_w Q-part units
#define QKVU 221184    // qkv_w total units
#define PU   73728     // proj_w units
__global__ void cvt_kernel(const float* __restrict__ x, const float* __restrict__ qkv_w,
                           const float* __restrict__ proj_w, __bf16* __restrict__ dst) {
    const int i = blockIdx.x * blockDim.x + threadIdx.x;
    if (i >= XU + QKVU + PU) return;
    const float* src;
    float sc = 1.f;
    if (i < XU) src = x + (size_t)i * 8;
    else if (i < XU + QKVU) {
        src = qkv_w + (size_t)(i - XU) * 8;
        if (i < XU + QU) sc = 0.125f;  // Q weight rows pre-scaled by softmax scale
    } else src = proj_w + (size_t)(i - XU - QKVU) * 8;
    f32x4 a = *(const f32x4*)src;
    f32x4 b = *(const f32x4*)(src + 4);
    bf16x8 o;
#pragma unroll
    for (int j = 0; j < 4; ++j) { o[j] = (__bf16)(a[j] * sc); o[j + 4] = (__bf16)(b[j] * sc); }
    *(bf16x8*)(dst + (size_t)i * 8) = o;
}

// ---------------- GEMM: C[M][ncol] = A[M][768] * Bw[ncol][768]^T + bias ----
template <int EPI>
__global__ __launch_bounds__(256, 4) void gemm_kernel(
    const __bf16* __restrict__ A, const __bf16* __restrict__ Bw,
    const float* __restrict__ bias,
    __bf16* __restrict__ qkbuf, __bf16* __restrict__ vtbuf,
    float* __restrict__ fout) {
    __shared__ __bf16 Alds[128 * 64];
    __shared__ __bf16 Blds[128 * 64];

    const int tid = threadIdx.x;
    const int l = tid & 63;
    const int w = tid >> 6;
    const int g = l >> 4, q16 = l & 15;
    const int mb = blockIdx.x * 128;
    const int nb = blockIdx.y * 128;
    const int wrb = (w >> 1) * 64;
    const int wcb = (w & 1) * 64;
    const int srow = w * 8 + (l >> 3);
    const int scol = (l & 7) * 8;

    f32x4 acc[4][4] = {};

    for (int kt = 0; kt < 12; ++kt) {
        const int kof = kt * 64 + scol;
#pragma unroll
        for (int i = 0; i < 4; ++i) {
            gload_lds16(&A[(size_t)(mb + i * 32 + srow) * CC + kof], &Alds[i * 2048 + w * 512]);
            gload_lds16(&Bw[(size_t)(nb + i * 32 + srow) * CC + kof], &Blds[i * 2048 + w * 512]);
        }
        __syncthreads();
#pragma unroll
        for (int c = 0; c < 2; ++c) {
            bf16x8 af[4], bfr[4];
#pragma unroll
            for (int m = 0; m < 4; ++m)
                af[m] = *(const bf16x8*)&Alds[(wrb + m * 16 + q16) * 64 + c * 32 + g * 8];
#pragma unroll
            for (int n = 0; n < 4; ++n)
                bfr[n] = *(const bf16x8*)&Blds[(wcb + n * 16 + q16) * 64 + c * 32 + g * 8];
#pragma unroll
            for (int m = 0; m < 4; ++m)
#pragma unroll
                for (int n = 0; n < 4; ++n)
                    acc[m][n] = mfma16(af[m], bfr[n], acc[m][n]);
        }
        __syncthreads();
    }

    // epilogue. C/D layout: col = q16 (+16*n), row = 4*g + r (+16*m)
    if constexpr (EPI == 0) {
        const int bbatch = mb / NN;
        const int tokb = mb % NN;
#pragma unroll
        for (int n = 0; n < 4; ++n) {
            const int colb = nb + wcb + n * 16;
            const int col = colb + q16;
            float bs = bias[col];
            if (colb < 2 * CC) {
                if (colb < CC) bs *= 0.125f;
#pragma unroll
                for (int m = 0; m < 4; ++m) {
                    const int row = mb + wrb + m * 16 + g * 4;
#pragma unroll
                    for (int r = 0; r < 4; ++r)
                        qkbuf[(size_t)(row + r) * 1536 + col] = (__bf16)(acc[m][n][r] + bs);
                }
            } else {
                const int dd = (col - 2 * CC) & 63;
                const int hh = (colb - 2 * CC) >> 6;
                __bf16* vp = vtbuf + ((size_t)(bbatch * HH + hh) * HD + dd) * NN;
#pragma unroll
                for (int m = 0; m < 4; ++m) {
                    const int tok = tokb + wrb + m * 16 + g * 4;
                    bf16x4 pk;
#pragma unroll
                    for (int r = 0; r < 4; ++r) pk[r] = (__bf16)(acc[m][n][r] + bs);
                    *(bf16x4*)&vp[tok] = pk;
                }
            }
        }
    } else {
#pragma unroll
        for (int n = 0; n < 4; ++n) {
            const int col = nb + wcb + n * 16 + q16;
            const float bs = bias[col];
#pragma unroll
            for (int m = 0; m < 4; ++m)
#pragma unroll
                for (int r = 0; r < 4; ++r)
                    fout[(size_t)(mb + wrb + m * 16 + g * 4 + r) * CC + col] = acc[m][n][r] + bs;
        }
    }
}

// ---------------- fused policy-softmax attention (online softmax) ----------
// ONE block per (b,h): grid 384, 512 threads (8 waves x 16 queries x 3 passes).
// Q, K, V ALL staged once into swizzled LDS (145.5 KB); passes barrier-free.
// Online softmax over 6 key-tiles of 64: per-thread hot state st[4]+oacc[4]
// (~32 VGPR) -- rounds 3-5 spilled to scratch (100-160 MB/dispatch) with
// st[24]/st[8] + reg-resident Q. Running max is over ALL keys (mask only
// gates e), matching the reference.
__global__ __launch_bounds__(512, 1) void attn_kernel(
    const __bf16* __restrict__ qkbuf, const __bf16* __restrict__ vtbuf,
    const float* __restrict__ policy, __bf16* __restrict__ attb) {
    __shared__ __bf16 Qlds[NN * HD];  // [row][128B], swz: byte ^= (row&7)<<4
    __shared__ __bf16 Klds[NN * HD];  // [row][128B], swz: byte ^= (row&7)<<4
    __shared__ __bf16 Vlds[HD * NN];  // [row][768B], swz: byte ^= (row&7)<<4
    __shared__ float pol[NN];

    const int tid = threadIdx.x;
    const int l = tid & 63;
    const int w = tid >> 6;
    const int g = l >> 4, q16 = l & 15;
    const int bh = blockIdx.x;
    const int b = bh / HH, h = bh % HH;

    // Q/K stage: chunk cs -> row cs>>3 (128B rows), in-row chunk (cs&7)^(row&7)
    const __bf16* qg = qkbuf + (size_t)b * NN * 1536 + h * HD;
    const __bf16* kg = qg + CC;
#pragma unroll
    for (int p = 0; p < 6; ++p) {
        const int cs = p * 512 + w * 64 + l;
        const int row = cs >> 3, cin = cs & 7;
        const size_t go = (size_t)row * 1536 + (size_t)((cin ^ (row & 7)) << 3);
        gload_lds16(&qg[go], &Qlds[(p * 512 + w * 64) * 8]);
        gload_lds16(&kg[go], &Klds[(p * 512 + w * 64) * 8]);
    }
    // V stage: rows of 48 chunks; XOR low 3 chunk bits (bijective within row)
    const __bf16* vg = vtbuf + (size_t)(b * HH + h) * HD * NN;
#pragma unroll
    for (int p = 0; p < 6; ++p) {
        const int cs = p * 512 + w * 64 + l;
        const int row = cs / 48, cin = cs - row * 48;
        gload_lds16(&vg[row * NN + ((cin ^ (row & 7)) << 3)], &Vlds[(p * 512 + w * 64) * 8]);
    }
    for (int i = tid; i < NN; i += 512) pol[i] = policy[b * NN + i];
    __syncthreads();  // drains DMA (vmcnt) + pol writes

    const int sw = (q16 & 7) << 4;  // row&7 == q16&7 for all rows we touch

#pragma unroll 1
    for (int ps = 0; ps < 3; ++ps) {
        const int qrow = ps * 128 + w * 16 + q16;
        const int qbyte0 = qrow * 128 + g * 16;
        const bf16x8 qf0 = *(const bf16x8*)((const char*)Qlds + (qbyte0 ^ sw));
        const bf16x8 qf1 = *(const bf16x8*)((const char*)Qlds + ((qbyte0 + 64) ^ sw));

        float m = -1e30f, sum = 0.f;
        f32x4 oacc[4] = {};

#pragma unroll 1
        for (int kt = 0; kt < 6; ++kt) {
            // S^T tile: st[t][r] = S[key = kt*64 + 16t + 4g + r][q = q16]
            f32x4 st[4];
            __builtin_amdgcn_s_setprio(1);
#pragma unroll
            for (int t = 0; t < 4; ++t) {
                const int byte0 = ((kt * 4 + t) * 16 + q16) * 128 + g * 16;
                bf16x8 k0 = *(const bf16x8*)((const char*)Klds + (byte0 ^ sw));
                bf16x8 k1 = *(const bf16x8*)((const char*)Klds + ((byte0 + 64) ^ sw));
                f32x4 z = {0.f, 0.f, 0.f, 0.f};
                st[t] = mfma16(k1, qf1, mfma16(k0, qf0, z));
            }
            __builtin_amdgcn_s_setprio(0);

            // tile max over ALL keys (unmasked, as in reference)
            float tmx = fmaxf(fmaxf(st[0][0], st[0][1]), fmaxf(st[0][2], st[0][3]));
#pragma unroll
            for (int t = 1; t < 4; ++t)
#pragma unroll
                for (int r = 0; r < 4; ++r) tmx = fmaxf(tmx, st[t][r]);
            tmx = fmaxf(tmx, __shfl_xor(tmx, 16));
            tmx = fmaxf(tmx, __shfl_xor(tmx, 32));

            // unconditional online rescale (uniform within each query group)
            const float newm = fmaxf(m, tmx);
            const float f = __expf(m - newm);  // first tile: exp(-inf) = 0
            m = newm;
            sum *= f;
#pragma unroll
            for (int db = 0; db < 4; ++db) oacc[db] *= f;

            // e = keep ? exp(s-m) : 0 ; keep = policy[key] | (key==q)
#pragma unroll
            for (int t = 0; t < 4; ++t)
#pragma unroll
                for (int r = 0; r < 4; ++r) {
                    const int key = kt * 64 + t * 16 + g * 4 + r;
                    const bool keep = (pol[key] > 0.5f) || (key == qrow);
                    const float e = keep ? __expf(st[t][r] - m) : 0.f;
                    st[t][r] = e;
                    sum += e;
                }

            // PV accumulate for this tile (P k-slots lane-local)
            __builtin_amdgcn_s_setprio(1);
#pragma unroll
            for (int c4 = 0; c4 < 2; ++c4) {
                bf16x8 pf;
#pragma unroll
                for (int r = 0; r < 4; ++r) {
                    pf[r] = (__bf16)st[2 * c4][r];
                    pf[r + 4] = (__bf16)st[2 * c4 + 1][r];
                }
                const int c = kt * 2 + c4;  // 32-key column group
#pragma unroll
                for (int db = 0; db < 4; ++db) {
                    const int byte0 = (db * 16 + q16) * 768 + c * 64 + g * 8;
                    bf16x4 v0 = *(const bf16x4*)((const char*)Vlds + (byte0 ^ sw));
                    bf16x4 v1 = *(const bf16x4*)((const char*)Vlds + ((byte0 + 32) ^ sw));
                    bf16x8 vf;
#pragma unroll
                    for (int r = 0; r < 4; ++r) { vf[r] = v0[r]; vf[r + 4] = v1[r]; }
                    oacc[db] = mfma16(vf, pf, oacc[db]);
                }
            }
            __builtin_amdgcn_s_setprio(0);
        }

        sum += __shfl_xor(sum, 16);
        sum += __shfl_xor(sum, 32);
        const float dinv = 1.f / (sum + 1e-6f);  // EPS/n numerator ~1e-9: dropped

        __bf16* op = attb + ((size_t)b * NN + qrow) * CC + h * HD;
#pragma unroll
        for (int db = 0; db < 4; ++db) {
            bf16x4 pk;
#pragma unroll
            for (int r = 0; r < 4; ++r) pk[r] = (__bf16)(oacc[db][r] * dinv);
            *(bf16x4*)&op[db * 16 + g * 4] = pk;
        }
    }
}

extern "C" void kernel_launch(void* const* d_in, const int* in_sizes, int n_in,
                              void* d_out, int out_size, void* d_ws, size_t ws_size,
                              hipStream_t stream) {
    (void)in_sizes; (void)n_in; (void)out_size; (void)ws_size;
    const float* x      = (const float*)d_in[0];
    const float* policy = (const float*)d_in[1];
    const float* qkv_w  = (const float*)d_in[2];
    const float* qkv_b  = (const float*)d_in[3];
    const float* proj_w = (const float*)d_in[4];
    const float* proj_b = (const float*)d_in[5];
    float* out = (float*)d_out;

    // workspace layout (bf16), total ~94.5 MB
    __bf16* xb    = (__bf16*)d_ws;                     // 12288*768
    __bf16* wqkv  = xb + (size_t)12288 * 768;          // 2304*768
    __bf16* wproj = wqkv + (size_t)2304 * 768;         // 768*768
    __bf16* qkbuf = wproj + (size_t)768 * 768;         // 12288*1536 (Q|K)
    __bf16* vtbuf = qkbuf + (size_t)12288 * 1536;      // 32*12*64*384 (V^T)
    __bf16* attb  = vtbuf + (size_t)BB * HH * HD * NN; // 12288*768

    const int units = XU + QKVU + PU;
    cvt_kernel<<<(units + 255) / 256, 256, 0, stream>>>(x, qkv_w, proj_w, xb);

    gemm_kernel<0><<<dim3(96, 18), 256, 0, stream>>>(xb, wqkv, qkv_b, qkbuf, vtbuf, nullptr);
    attn_kernel<<<384, 512, 0, stream>>>(qkbuf, vtbuf, policy, attb);
    gemm_kernel<1><<<dim3(96, 6), 256, 0, stream>>>(attb, wproj, proj_b, nullptr, nullptr, out);
}